// Round 14
// baseline (13359.563 us; speedup 1.0000x reference)
//
#include <hip/hip_runtime.h>

#define TSTEPS 784
#define BATCH  256
#define HDIM   512
#define NCLS   10
#define NGRP   16
#define NWG    32  // 2 WGs per group: gb = wg&15, half = wg>>4; partner = wg^16

typedef __bf16 bf16x8 __attribute__((ext_vector_type(8)));
typedef float  f32x4  __attribute__((ext_vector_type(4)));
typedef unsigned uint4v __attribute__((ext_vector_type(4)));
typedef unsigned long long u64;
typedef unsigned short u16;

static __device__ __forceinline__ u16 f2bf(float f) {
  unsigned u = __builtin_bit_cast(unsigned, f);
  u += 0x7fffu + ((u >> 16) & 1u);
  return (u16)(u >> 16);
}
static __device__ __forceinline__ float bf2f(unsigned s) {
  unsigned u = s << 16;
  return __builtin_bit_cast(float, u);
}
static __device__ __forceinline__ u64 ald64(const u64* p) {
  return __hip_atomic_load(p, __ATOMIC_RELAXED, __HIP_MEMORY_SCOPE_AGENT);
}
static __device__ __forceinline__ void ast16(u16* p, u16 v) {
  __hip_atomic_store(p, v, __ATOMIC_RELAXED, __HIP_MEMORY_SCOPE_AGENT);
}
static __device__ __forceinline__ unsigned aldf(const unsigned* p) {
  return __hip_atomic_load(p, __ATOMIC_RELAXED, __HIP_MEMORY_SCOPE_AGENT);
}
static __device__ __forceinline__ void astf(unsigned* p, unsigned v) {
  __hip_atomic_store(p, v, __ATOMIC_RELAXED, __HIP_MEMORY_SCOPE_AGENT);
}

// ---------------- xp[t][b] = inputs[b][perm[t]] ----------------
__global__ __launch_bounds__(256) void gather_xp(const float* __restrict__ in,
                                                 const int* __restrict__ perm,
                                                 float* __restrict__ xp) {
  int t = blockIdx.x;
  int b = threadIdx.x;
  int p = perm[t];
  p = (p < 0) ? 0 : (p >= TSTEPS ? TSTEPS - 1 : p);
  xp[t * BATCH + b] = in[b * TSTEPS + p];
}

// ---------------- X = (triu(W,1) - triu(W,1)^T) / 32 ----------------
__global__ __launch_bounds__(256) void build_X(const float* __restrict__ W,
                                               float* __restrict__ X) {
  int idx = blockIdx.x * 256 + threadIdx.x;
  int i = idx >> 9, j = idx & 511;
  float v = 0.f;
  if (j > i) v = W[i * HDIM + j];
  else if (i > j) v = -W[j * HDIM + i];
  X[idx] = v * 0.03125f;
}

// ---------------- P = coef*X + I ----------------
__global__ __launch_bounds__(256) void axpyI(float* __restrict__ P,
                                             const float* __restrict__ X, float coef) {
  int idx = blockIdx.x * 256 + threadIdx.x;
  int i = idx >> 9, j = idx & 511;
  P[idx] = coef * X[idx] + ((i == j) ? 1.f : 0.f);
}

// ---------------- C = alpha*A*B (+I), 512^3 fp32 [R2-R12 proven] ----------------
// expm chain needs fp32-class accuracy (R9: split-bf16 here -> absmax 12).
__global__ __launch_bounds__(256) void gemm512(float* __restrict__ C,
                                               const float* __restrict__ A,
                                               const float* __restrict__ B,
                                               float alpha, int addI) {
  __shared__ float As[16][68];
  __shared__ float Bs[16][68];
  const int tx = threadIdx.x, ty = threadIdx.y;
  const int tid = ty * 16 + tx;
  const int ib = blockIdx.y, jb = blockIdx.x;
  const int ra = tid >> 2, ca = (tid & 3) << 2;
  const int rb = tid >> 4, cb = (tid & 15) << 2;
  float acc[4][4] = {};
  for (int kt = 0; kt < HDIM / 16; ++kt) {
    f32x4 av = *(const f32x4*)(A + (ib * 64 + ra) * HDIM + kt * 16 + ca);
    f32x4 bv = *(const f32x4*)(B + (kt * 16 + rb) * HDIM + jb * 64 + cb);
    __syncthreads();
    As[ca + 0][ra] = av[0];
    As[ca + 1][ra] = av[1];
    As[ca + 2][ra] = av[2];
    As[ca + 3][ra] = av[3];
    *(f32x4*)&Bs[rb][cb] = bv;
    __syncthreads();
#pragma unroll
    for (int kk = 0; kk < 16; ++kk) {
      f32x4 a4 = *(const f32x4*)&As[kk][ty << 2];
      f32x4 b4 = *(const f32x4*)&Bs[kk][tx << 2];
#pragma unroll
      for (int u = 0; u < 4; ++u)
#pragma unroll
        for (int v = 0; v < 4; ++v) acc[u][v] = fmaf(a4[u], b4[v], acc[u][v]);
    }
  }
#pragma unroll
  for (int u = 0; u < 4; ++u)
#pragma unroll
    for (int v = 0; v < 4; ++v) {
      int r = ib * 64 + (ty << 2) + u, c = jb * 64 + (tx << 2) + v;
      float val = alpha * acc[u][v];
      if (addI && r == c) val += 1.f;
      C[r * HDIM + c] = val;
    }
}

// ---------------- persistent RNN scan: 2 WGs per group, half-exchange ----------------
// 32 WGs x 1024 thr (16 waves). gb = wg&15 (batch rows gb*16..+16), half = wg>>4
// (cols half*256..+256; wave w owns 16 cols). B hi/lo = 128 AGPR/wave [proven budget].
// Own half of h lives in LDS (double-buffered swizzled u16 planes) and is ALSO
// stored to global (agent-scope, R10-proven) for the partner. Per step:
//   (a) own-half MFMAs (ki of own K range) -- runs while partner's data drains
//   (b) poll partner flag >= t  (c) stage partner 256 cols (1 u64/thread/plane)
//   (d) __syncthreads  (e) partner-half MFMAs  (f) epilogue: LDS own + global own
//   (g) drain + __syncthreads  (h) flag t+1.
// Race-freedom: I write h_{t+1} into the h_{t-1} buffer only after seeing partner
// flag >= t, which the partner emits only after its reads of h_{t-1} completed
// (its loads precede its drain precede its flag). All polls valve-bounded.
__global__ __launch_bounds__(1024, 1) void rnn_main(
    const float* __restrict__ xp, const float* __restrict__ Borth,
    const float* __restrict__ W_in, const float* __restrict__ b_mod,
    const float* __restrict__ W_lin, const float* __restrict__ b_lin,
    u16* __restrict__ h0hi, u16* __restrict__ h0lo, u16* __restrict__ h1hi,
    u16* __restrict__ h1lo, unsigned* __restrict__ flags, float* __restrict__ out) {
  __shared__ unsigned tHi[2 * 4096];  // 2 bufs x 16 KB (u16 hi plane, swizzled)
  __shared__ unsigned tLo[2 * 4096];

  const int wg = blockIdx.x;
  const int gb = wg & 15;
  const int half = wg >> 4;
  const int tid = threadIdx.x;
  const int wave = tid >> 6;
  const int lane = tid & 63;
  const int quad = lane >> 4;
  const int l16 = lane & 15;
  const int colg = (half << 8) + (wave << 4) + l16;  // this lane's output column
  const unsigned swz = (unsigned)((l16 & 7) << 2);

  // B fragments: 16 cols/wave, hi/lo = 128 AGPRs [R10-proven budget/numerics]
  bf16x8 Bfh[16], Bfl[16];
#pragma unroll
  for (int ki = 0; ki < 16; ++ki) {
#pragma unroll
    for (int j = 0; j < 8; ++j) {
      int k = (ki << 5) + (quad << 3) + j;
      float v = Borth[k * HDIM + colg];
      u16 hb = f2bf(v);
      u16 lb = f2bf(v - bf2f(hb));
      Bfh[ki][j] = __builtin_bit_cast(__bf16, hb);
      Bfl[ki][j] = __builtin_bit_cast(__bf16, lb);
    }
  }
  const float win = W_in[colg];
  const float bm = b_mod[colg];

  u16* const G0h = h0hi + (gb << 13);
  u16* const G0l = h0lo + (gb << 13);
  u16* const G1h = h1hi + (gb << 13);
  u16* const G1l = h1lo + (gb << 13);
  unsigned* const myflag = flags + wg * 32;
  unsigned* const pflag = flags + (wg ^ 16) * 32;
  const int P = (1 - half) << 8;  // partner col base (0 or 256)
  const int kiOwn = half << 3;    // own K range: ki in [kiOwn, kiOwn+8)
  const int kiPar = (1 - half) << 3;

  // zero tile buffer 0 (h_0 = 0)
#pragma unroll
  for (int i = 0; i < 4; ++i) {
    tHi[tid + (i << 10)] = 0u;
    tLo[tid + (i << 10)] = 0u;
  }
  __syncthreads();

  for (int t = 0; t < TSTEPS; ++t) {
    const u16* cH = (t & 1) ? G1h : G0h;
    const u16* cL = (t & 1) ? G1l : G0l;
    u16* nH = (t & 1) ? G0h : G1h;
    u16* nL = (t & 1) ? G0l : G1l;
    unsigned* curTh = tHi + ((t & 1) << 12);
    unsigned* curTl = tLo + ((t & 1) << 12);
    unsigned* nxtTh = tHi + ((1 - (t & 1)) << 12);
    unsigned* nxtTl = tLo + ((1 - (t & 1)) << 12);

    const f32x4 xps = *(const f32x4*)(xp + t * BATCH + (gb << 4) + (quad << 2));

    // ---- (a) own-half MFMAs first: hides partner drain/propagate latency ----
    f32x4 a_hh = {0.f, 0.f, 0.f, 0.f};
    f32x4 a_lh = {0.f, 0.f, 0.f, 0.f};
    f32x4 a_hl = {0.f, 0.f, 0.f, 0.f};
#pragma unroll
    for (int kk = 0; kk < 8; ++kk) {
      int ki = kiOwn + kk;
      unsigned off = ((unsigned)l16 << 8) + (((unsigned)((ki << 4) + (quad << 2))) ^ swz);
      bf16x8 ah = __builtin_bit_cast(bf16x8, *(const uint4v*)(curTh + off));
      bf16x8 al = __builtin_bit_cast(bf16x8, *(const uint4v*)(curTl + off));
      a_hh = __builtin_amdgcn_mfma_f32_16x16x32_bf16(ah, Bfh[ki], a_hh, 0, 0, 0);
      a_lh = __builtin_amdgcn_mfma_f32_16x16x32_bf16(al, Bfh[ki], a_lh, 0, 0, 0);
      a_hl = __builtin_amdgcn_mfma_f32_16x16x32_bf16(ah, Bfl[ki], a_hl, 0, 0, 0);
    }

    // ---- (b) wait for partner's h_t ----
    {
      int spin = 0;
      while (aldf(pflag) < (unsigned)t) {
        __builtin_amdgcn_s_sleep(1);
        if (++spin > (1 << 18)) break;  // anti-hang valve (wrong answer > hang)
      }
    }

    // ---- (c) stage partner half: wave w stages row w; 1 u64/thread/plane ----
    u64 qh = ald64((const u64*)cH + wave * 128 + (P >> 2) + lane);
    u64 ql = ald64((const u64*)cL + wave * 128 + (P >> 2) + lane);
    {
      unsigned du = (unsigned)(P >> 1) + ((unsigned)lane << 1);
      unsigned phys = ((unsigned)wave << 8) | (du ^ ((wave & 7) << 2));
      *(u64*)(curTh + phys) = qh;
      *(u64*)(curTl + phys) = ql;
    }
    __syncthreads();  // (d) stage writes -> partner-half reads

    // ---- (e) partner-half MFMAs ----
#pragma unroll
    for (int kk = 0; kk < 8; ++kk) {
      int ki = kiPar + kk;
      unsigned off = ((unsigned)l16 << 8) + (((unsigned)((ki << 4) + (quad << 2))) ^ swz);
      bf16x8 ah = __builtin_bit_cast(bf16x8, *(const uint4v*)(curTh + off));
      bf16x8 al = __builtin_bit_cast(bf16x8, *(const uint4v*)(curTl + off));
      a_hh = __builtin_amdgcn_mfma_f32_16x16x32_bf16(ah, Bfh[ki], a_hh, 0, 0, 0);
      a_lh = __builtin_amdgcn_mfma_f32_16x16x32_bf16(al, Bfh[ki], a_lh, 0, 0, 0);
      a_hl = __builtin_amdgcn_mfma_f32_16x16x32_bf16(ah, Bfl[ki], a_hl, 0, 0, 0);
    }

    // ---- (f) epilogue: C/D row=quad*4+r, col=l16 [proven]; LDS own + global own ----
#pragma unroll
    for (int r = 0; r < 4; ++r) {
      float pre = a_hh[r] + a_lh[r] + a_hl[r] + xps[r] * win;
      float mm = fmaxf(fabsf(pre) + bm, 0.f);
      float hv = (pre > 0.f) ? mm : ((pre < 0.f) ? -mm : 0.f);
      int row = (quad << 2) + r;
      u16 hbv = f2bf(hv);
      u16 lbv = f2bf(hv - bf2f(hbv));
      ast16(nH + (row << 9) + colg, hbv);  // global (for partner)
      ast16(nL + (row << 9) + colg, lbv);
      unsigned p2 = ((unsigned)row << 8) | (((unsigned)(colg >> 1)) ^ ((row & 7) << 2));
      ((u16*)nxtTh)[p2 * 2 + (colg & 1)] = hbv;  // LDS (own next tile)
      ((u16*)nxtTl)[p2 * 2 + (colg & 1)] = lbv;
    }
    // ---- (g) drain own global stores (per-wave), converge all 16 waves ----
    asm volatile("s_waitcnt vmcnt(0)" ::: "memory");
    __syncthreads();
    // ---- (h) flag completion of step t ----
    if (tid == 0) astf(myflag, (unsigned)(t + 1));
  }

  // ---- head (half 0 only): wait partner h_784, stage its half of buf0, GEMV ----
  if (half == 0) {
    {
      int spin = 0;
      while (aldf(pflag) < (unsigned)TSTEPS) {
        __builtin_amdgcn_s_sleep(1);
        if (++spin > (1 << 20)) break;  // anti-hang valve
      }
    }
    u64 qh = ald64((const u64*)G0h + wave * 128 + 64 + lane);  // partner cols 256..511
    u64 ql = ald64((const u64*)G0l + wave * 128 + 64 + lane);
    {
      unsigned du = 128u + ((unsigned)lane << 1);
      unsigned phys = ((unsigned)wave << 8) | (du ^ ((wave & 7) << 2));
      *(u64*)(tHi + phys) = qh;  // buffer 0 (owns h_784: t=783 writes buf0)
      *(u64*)(tLo + phys) = ql;
    }
    __syncthreads();
    if (tid < 256) {
      int row = tid >> 4;
      int cls = tid & 15;
      if (cls < NCLS) {
        float s = b_lin[cls];
        const float* wl = W_lin + cls * HDIM;
        unsigned rsw = (unsigned)((row & 7) << 2);
        for (int k = 0; k < HDIM; ++k) {
          unsigned phys = ((unsigned)row << 8) | (((unsigned)(k >> 1)) ^ rsw);
          unsigned slot = phys * 2 + (unsigned)(k & 1);
          s = fmaf(bf2f(((const u16*)tHi)[slot]) + bf2f(((const u16*)tLo)[slot]), wl[k], s);
        }
        out[((gb << 4) + row) * NCLS + cls] = s;
      }
    }
  }
}

extern "C" void kernel_launch(void* const* d_in, const int* in_sizes, int n_in,
                              void* d_out, int out_size, void* d_ws, size_t ws_size,
                              hipStream_t stream) {
  const float* inputs = (const float*)d_in[0];  // 256x784
  const int* perm = (const int*)d_in[1];        // 784 (int64 -> int32 by harness)
  const float* W_skew = (const float*)d_in[2];  // 512x512
  const float* W_in = (const float*)d_in[3];    // 512
  const float* b_mod = (const float*)d_in[4];   // 512
  const float* W_lin = (const float*)d_in[5];   // 10x512
  const float* b_lin = (const float*)d_in[6];   // 10
  float* out = (float*)d_out;

  char* ws = (char*)d_ws;
  unsigned* flags = (unsigned*)ws;            // 32 WGs x 128 B = 4 KB (8 KB reserved)
  u16* h0hi = (u16*)(ws + 8192);              // 4 planes x 256 KB = 1 MB
  u16* h0lo = h0hi + BATCH * HDIM;
  u16* h1hi = h0lo + BATCH * HDIM;
  u16* h1lo = h1hi + BATCH * HDIM;
  float* xp = (float*)(h1lo + BATCH * HDIM);  // 0.77 MB
  float* X = xp + TSTEPS * BATCH;             // 1 MB
  float* P = X + HDIM * HDIM;                 // 1 MB
  float* Q = P + HDIM * HDIM;                 // 1 MB  (total ~4.9 MB)

  hipMemsetAsync(flags, 0, 8192, stream);
  hipMemsetAsync(h0hi, 0, (size_t)BATCH * HDIM * 2 * sizeof(u16), stream);  // h_0 = 0

  gather_xp<<<TSTEPS, 256, 0, stream>>>(inputs, perm, xp);
  build_X<<<(HDIM * HDIM) / 256, 256, 0, stream>>>(W_skew, X);

  // expm(A) = (T6(A/32))^(2^5), Horner -- fp32 gemm512 [proven numerics]
  axpyI<<<(HDIM * HDIM) / 256, 256, 0, stream>>>(P, X, 1.f / 6.f);
  float* a = P;
  float* b = Q;
  for (int k = 5; k >= 1; --k) {
    gemm512<<<dim3(8, 8), dim3(16, 16), 0, stream>>>(b, X, a, 1.f / (float)k, 1);
    float* tmp = a; a = b; b = tmp;
  }
  for (int i = 0; i < 5; ++i) {
    gemm512<<<dim3(8, 8), dim3(16, 16), 0, stream>>>(b, a, a, 1.f, 0);
    float* tmp = a; a = b; b = tmp;
  }
  // a == P (10 swaps -> back to P)

  rnn_main<<<NWG, 1024, 0, stream>>>(xp, a, W_in, b_mod, W_lin, b_lin, h0hi, h0lo,
                                     h1hi, h1lo, flags, out);
  (void)in_sizes; (void)n_in; (void)out_size; (void)ws_size;
}

// Round 15
// 8089.693 us; speedup vs baseline: 1.6514x; 1.6514x over previous
//
#include <hip/hip_runtime.h>

#define TSTEPS 784
#define BATCH  256
#define HDIM   512
#define NCLS   10
#define NGRP   16
#define NWG    32  // 2 WGs per group: gb = wg&15, half = wg>>4; partner = wg^16

typedef __bf16 bf16x8 __attribute__((ext_vector_type(8)));
typedef float  f32x4  __attribute__((ext_vector_type(4)));
typedef unsigned uint4v __attribute__((ext_vector_type(4)));
typedef unsigned long long u64;
typedef unsigned short u16;

static __device__ __forceinline__ u16 f2bf(float f) {
  unsigned u = __builtin_bit_cast(unsigned, f);
  u += 0x7fffu + ((u >> 16) & 1u);
  return (u16)(u >> 16);
}
static __device__ __forceinline__ float bf2f(unsigned s) {
  unsigned u = s << 16;
  return __builtin_bit_cast(float, u);
}
static __device__ __forceinline__ u64 ald64(const u64* p) {
  return __hip_atomic_load(p, __ATOMIC_RELAXED, __HIP_MEMORY_SCOPE_AGENT);
}
static __device__ __forceinline__ void ast16(u16* p, u16 v) {
  __hip_atomic_store(p, v, __ATOMIC_RELAXED, __HIP_MEMORY_SCOPE_AGENT);
}
static __device__ __forceinline__ unsigned aldf(const unsigned* p) {
  return __hip_atomic_load(p, __ATOMIC_RELAXED, __HIP_MEMORY_SCOPE_AGENT);
}
static __device__ __forceinline__ void astf(unsigned* p, unsigned v) {
  __hip_atomic_store(p, v, __ATOMIC_RELAXED, __HIP_MEMORY_SCOPE_AGENT);
}

// ---------------- xp[t][b] = inputs[b][perm[t]] ----------------
__global__ __launch_bounds__(256) void gather_xp(const float* __restrict__ in,
                                                 const int* __restrict__ perm,
                                                 float* __restrict__ xp) {
  int t = blockIdx.x;
  int b = threadIdx.x;
  int p = perm[t];
  p = (p < 0) ? 0 : (p >= TSTEPS ? TSTEPS - 1 : p);
  xp[t * BATCH + b] = in[b * TSTEPS + p];
}

// ---------------- X = (triu(W,1) - triu(W,1)^T) / 32 ----------------
__global__ __launch_bounds__(256) void build_X(const float* __restrict__ W,
                                               float* __restrict__ X) {
  int idx = blockIdx.x * 256 + threadIdx.x;
  int i = idx >> 9, j = idx & 511;
  float v = 0.f;
  if (j > i) v = W[i * HDIM + j];
  else if (i > j) v = -W[j * HDIM + i];
  X[idx] = v * 0.03125f;
}

// ---------------- P = coef*X + I ----------------
__global__ __launch_bounds__(256) void axpyI(float* __restrict__ P,
                                             const float* __restrict__ X, float coef) {
  int idx = blockIdx.x * 256 + threadIdx.x;
  int i = idx >> 9, j = idx & 511;
  P[idx] = coef * X[idx] + ((i == j) ? 1.f : 0.f);
}

// ---------------- C = alpha*A*B (+I), 512^3 fp32 [R2-R12 proven] ----------------
__global__ __launch_bounds__(256) void gemm512(float* __restrict__ C,
                                               const float* __restrict__ A,
                                               const float* __restrict__ B,
                                               float alpha, int addI) {
  __shared__ float As[16][68];
  __shared__ float Bs[16][68];
  const int tx = threadIdx.x, ty = threadIdx.y;
  const int tid = ty * 16 + tx;
  const int ib = blockIdx.y, jb = blockIdx.x;
  const int ra = tid >> 2, ca = (tid & 3) << 2;
  const int rb = tid >> 4, cb = (tid & 15) << 2;
  float acc[4][4] = {};
  for (int kt = 0; kt < HDIM / 16; ++kt) {
    f32x4 av = *(const f32x4*)(A + (ib * 64 + ra) * HDIM + kt * 16 + ca);
    f32x4 bv = *(const f32x4*)(B + (kt * 16 + rb) * HDIM + jb * 64 + cb);
    __syncthreads();
    As[ca + 0][ra] = av[0];
    As[ca + 1][ra] = av[1];
    As[ca + 2][ra] = av[2];
    As[ca + 3][ra] = av[3];
    *(f32x4*)&Bs[rb][cb] = bv;
    __syncthreads();
#pragma unroll
    for (int kk = 0; kk < 16; ++kk) {
      f32x4 a4 = *(const f32x4*)&As[kk][ty << 2];
      f32x4 b4 = *(const f32x4*)&Bs[kk][tx << 2];
#pragma unroll
      for (int u = 0; u < 4; ++u)
#pragma unroll
        for (int v = 0; v < 4; ++v) acc[u][v] = fmaf(a4[u], b4[v], acc[u][v]);
    }
  }
#pragma unroll
  for (int u = 0; u < 4; ++u)
#pragma unroll
    for (int v = 0; v < 4; ++v) {
      int r = ib * 64 + (ty << 2) + u, c = jb * 64 + (tx << 2) + v;
      float val = alpha * acc[u][v];
      if (addI && r == c) val += 1.f;
      C[r * HDIM + c] = val;
    }
}

// ---------------- the 2-WG scan body, HALF is COMPILE-TIME ----------------
// R14's fatal flaw: Bfh[kiOwn+kk] with runtime kiOwn (blockIdx-derived) ->
// dynamic register-array indexing -> full spill to scratch (VGPR_Count=40,
// 13-43 ms). Templating HALF makes every fragment index a literal.
template <int HALF>
static __device__ void run_scan(int gb, int tid, const float* __restrict__ xp,
                                const float* __restrict__ Borth,
                                const float* __restrict__ W_in,
                                const float* __restrict__ b_mod,
                                const float* __restrict__ W_lin,
                                const float* __restrict__ b_lin, u16* h0hi, u16* h0lo,
                                u16* h1hi, u16* h1lo, unsigned* flags,
                                float* __restrict__ out, unsigned* tHi, unsigned* tLo) {
  const int wave = tid >> 6;
  const int lane = tid & 63;
  const int quad = lane >> 4;
  const int l16 = lane & 15;
  constexpr int P = (1 - HALF) << 8;     // partner col base
  constexpr int kiOwn = HALF << 3;       // own K range base (compile-time!)
  constexpr int kiPar = (1 - HALF) << 3;
  const int colg = (HALF << 8) + (wave << 4) + l16;
  const unsigned swz = (unsigned)((l16 & 7) << 2);
  const int wg = (HALF << 4) | gb;

  // B fragments: 16 cols/wave, hi/lo = 128 AGPRs; ALL indices compile-time
  bf16x8 Bfh[16], Bfl[16];
#pragma unroll
  for (int ki = 0; ki < 16; ++ki) {
#pragma unroll
    for (int j = 0; j < 8; ++j) {
      int k = (ki << 5) + (quad << 3) + j;
      float v = Borth[k * HDIM + colg];
      u16 hb = f2bf(v);
      u16 lb = f2bf(v - bf2f(hb));
      Bfh[ki][j] = __builtin_bit_cast(__bf16, hb);
      Bfl[ki][j] = __builtin_bit_cast(__bf16, lb);
    }
  }
  const float win = W_in[colg];
  const float bm = b_mod[colg];

  u16* const G0h = h0hi + (gb << 13);
  u16* const G0l = h0lo + (gb << 13);
  u16* const G1h = h1hi + (gb << 13);
  u16* const G1l = h1lo + (gb << 13);
  unsigned* const myflag = flags + wg * 32;
  unsigned* const pflag = flags + (wg ^ 16) * 32;

  // zero tile buffer 0 (h_0 = 0)
#pragma unroll
  for (int i = 0; i < 4; ++i) {
    tHi[tid + (i << 10)] = 0u;
    tLo[tid + (i << 10)] = 0u;
  }
  __syncthreads();

  for (int t = 0; t < TSTEPS; ++t) {
    const u16* cH = (t & 1) ? G1h : G0h;
    const u16* cL = (t & 1) ? G1l : G0l;
    u16* nH = (t & 1) ? G0h : G1h;
    u16* nL = (t & 1) ? G0l : G1l;
    unsigned* curTh = tHi + ((t & 1) << 12);
    unsigned* curTl = tLo + ((t & 1) << 12);
    unsigned* nxtTh = tHi + ((1 - (t & 1)) << 12);
    unsigned* nxtTl = tLo + ((1 - (t & 1)) << 12);

    const f32x4 xps = *(const f32x4*)(xp + t * BATCH + (gb << 4) + (quad << 2));

    // ---- (a) own-half MFMAs first: hides partner drain/propagate latency ----
    f32x4 a_hh = {0.f, 0.f, 0.f, 0.f};
    f32x4 a_lh = {0.f, 0.f, 0.f, 0.f};
    f32x4 a_hl = {0.f, 0.f, 0.f, 0.f};
#pragma unroll
    for (int kk = 0; kk < 8; ++kk) {
      constexpr int base = kiOwn;  // literal
      unsigned off =
          ((unsigned)l16 << 8) + (((unsigned)(((base + kk) << 4) + (quad << 2))) ^ swz);
      bf16x8 ah = __builtin_bit_cast(bf16x8, *(const uint4v*)(curTh + off));
      bf16x8 al = __builtin_bit_cast(bf16x8, *(const uint4v*)(curTl + off));
      a_hh = __builtin_amdgcn_mfma_f32_16x16x32_bf16(ah, Bfh[base + kk], a_hh, 0, 0, 0);
      a_lh = __builtin_amdgcn_mfma_f32_16x16x32_bf16(al, Bfh[base + kk], a_lh, 0, 0, 0);
      a_hl = __builtin_amdgcn_mfma_f32_16x16x32_bf16(ah, Bfl[base + kk], a_hl, 0, 0, 0);
    }

    // ---- (b) wait for partner's h_t ----
    {
      int spin = 0;
      while (aldf(pflag) < (unsigned)t) {
        __builtin_amdgcn_s_sleep(1);
        if (++spin > (1 << 18)) break;  // anti-hang valve
      }
    }

    // ---- (c) stage partner half: wave w stages row w; 1 u64/thread/plane ----
    u64 qh = ald64((const u64*)cH + wave * 128 + (P >> 2) + lane);
    u64 ql = ald64((const u64*)cL + wave * 128 + (P >> 2) + lane);
    {
      unsigned du = (unsigned)(P >> 1) + ((unsigned)lane << 1);
      unsigned phys = ((unsigned)wave << 8) | (du ^ ((wave & 7) << 2));
      *(u64*)(curTh + phys) = qh;
      *(u64*)(curTl + phys) = ql;
    }
    __syncthreads();  // (d) stage writes -> partner-half reads

    // ---- (e) partner-half MFMAs ----
#pragma unroll
    for (int kk = 0; kk < 8; ++kk) {
      constexpr int base = kiPar;  // literal
      unsigned off =
          ((unsigned)l16 << 8) + (((unsigned)(((base + kk) << 4) + (quad << 2))) ^ swz);
      bf16x8 ah = __builtin_bit_cast(bf16x8, *(const uint4v*)(curTh + off));
      bf16x8 al = __builtin_bit_cast(bf16x8, *(const uint4v*)(curTl + off));
      a_hh = __builtin_amdgcn_mfma_f32_16x16x32_bf16(ah, Bfh[base + kk], a_hh, 0, 0, 0);
      a_lh = __builtin_amdgcn_mfma_f32_16x16x32_bf16(al, Bfh[base + kk], a_lh, 0, 0, 0);
      a_hl = __builtin_amdgcn_mfma_f32_16x16x32_bf16(ah, Bfl[base + kk], a_hl, 0, 0, 0);
    }

    // ---- (f) epilogue: C/D row=quad*4+r, col=l16 [proven]; LDS own + global own ----
#pragma unroll
    for (int r = 0; r < 4; ++r) {
      float pre = a_hh[r] + a_lh[r] + a_hl[r] + xps[r] * win;
      float mm = fmaxf(fabsf(pre) + bm, 0.f);
      float hv = (pre > 0.f) ? mm : ((pre < 0.f) ? -mm : 0.f);
      int row = (quad << 2) + r;
      u16 hbv = f2bf(hv);
      u16 lbv = f2bf(hv - bf2f(hbv));
      ast16(nH + (row << 9) + colg, hbv);  // global (for partner)
      ast16(nL + (row << 9) + colg, lbv);
      unsigned p2 = ((unsigned)row << 8) | (((unsigned)(colg >> 1)) ^ ((row & 7) << 2));
      ((u16*)nxtTh)[p2 * 2 + (colg & 1)] = hbv;  // LDS (own next tile)
      ((u16*)nxtTl)[p2 * 2 + (colg & 1)] = lbv;
    }
    // ---- (g) drain own global stores (per-wave), converge all 16 waves ----
    asm volatile("s_waitcnt vmcnt(0)" ::: "memory");
    __syncthreads();
    // ---- (h) flag completion of step t ----
    if (tid == 0) astf(myflag, (unsigned)(t + 1));
  }

  // ---- head (half 0 only): wait partner h_784, stage its half of buf0, GEMV ----
  if constexpr (HALF == 0) {
    {
      int spin = 0;
      while (aldf(pflag) < (unsigned)TSTEPS) {
        __builtin_amdgcn_s_sleep(1);
        if (++spin > (1 << 20)) break;  // anti-hang valve
      }
    }
    u64 qh = ald64((const u64*)G0h + wave * 128 + 64 + lane);  // partner cols 256..511
    u64 ql = ald64((const u64*)G0l + wave * 128 + 64 + lane);
    {
      unsigned du = 128u + ((unsigned)lane << 1);
      unsigned phys = ((unsigned)wave << 8) | (du ^ ((wave & 7) << 2));
      *(u64*)(tHi + phys) = qh;  // buffer 0 (h_784: t=783 writes buf0)
      *(u64*)(tLo + phys) = ql;
    }
    __syncthreads();
    if (tid < 256) {
      int row = tid >> 4;
      int cls = tid & 15;
      if (cls < NCLS) {
        float s = b_lin[cls];
        const float* wl = W_lin + cls * HDIM;
        unsigned rsw = (unsigned)((row & 7) << 2);
        for (int k = 0; k < HDIM; ++k) {
          unsigned phys = ((unsigned)row << 8) | (((unsigned)(k >> 1)) ^ rsw);
          unsigned slot = phys * 2 + (unsigned)(k & 1);
          s = fmaf(bf2f(((const u16*)tHi)[slot]) + bf2f(((const u16*)tLo)[slot]), wl[k], s);
        }
        out[((gb << 4) + row) * NCLS + cls] = s;
      }
    }
  }
}

// ---------------- persistent RNN scan, 2 WGs/group ----------------
__global__ __launch_bounds__(1024, 1) void rnn_main(
    const float* __restrict__ xp, const float* __restrict__ Borth,
    const float* __restrict__ W_in, const float* __restrict__ b_mod,
    const float* __restrict__ W_lin, const float* __restrict__ b_lin,
    u16* __restrict__ h0hi, u16* __restrict__ h0lo, u16* __restrict__ h1hi,
    u16* __restrict__ h1lo, unsigned* __restrict__ flags, float* __restrict__ out) {
  __shared__ unsigned tHi[2 * 4096];  // 2 bufs x 16 KB (u16 hi plane, swizzled)
  __shared__ unsigned tLo[2 * 4096];

  const int wg = blockIdx.x;
  const int gb = wg & 15;
  const int tid = threadIdx.x;

  if ((wg >> 4) == 0)
    run_scan<0>(gb, tid, xp, Borth, W_in, b_mod, W_lin, b_lin, h0hi, h0lo, h1hi, h1lo,
                flags, out, tHi, tLo);
  else
    run_scan<1>(gb, tid, xp, Borth, W_in, b_mod, W_lin, b_lin, h0hi, h0lo, h1hi, h1lo,
                flags, out, tHi, tLo);
}

extern "C" void kernel_launch(void* const* d_in, const int* in_sizes, int n_in,
                              void* d_out, int out_size, void* d_ws, size_t ws_size,
                              hipStream_t stream) {
  const float* inputs = (const float*)d_in[0];  // 256x784
  const int* perm = (const int*)d_in[1];        // 784 (int64 -> int32 by harness)
  const float* W_skew = (const float*)d_in[2];  // 512x512
  const float* W_in = (const float*)d_in[3];    // 512
  const float* b_mod = (const float*)d_in[4];   // 512
  const float* W_lin = (const float*)d_in[5];   // 10x512
  const float* b_lin = (const float*)d_in[6];   // 10
  float* out = (float*)d_out;

  char* ws = (char*)d_ws;
  unsigned* flags = (unsigned*)ws;            // 32 WGs x 128 B = 4 KB (8 KB reserved)
  u16* h0hi = (u16*)(ws + 8192);              // 4 planes x 256 KB = 1 MB
  u16* h0lo = h0hi + BATCH * HDIM;
  u16* h1hi = h0lo + BATCH * HDIM;
  u16* h1lo = h1hi + BATCH * HDIM;
  float* xp = (float*)(h1lo + BATCH * HDIM);  // 0.77 MB
  float* X = xp + TSTEPS * BATCH;             // 1 MB
  float* P = X + HDIM * HDIM;                 // 1 MB
  float* Q = P + HDIM * HDIM;                 // 1 MB  (total ~4.9 MB)

  hipMemsetAsync(flags, 0, 8192, stream);
  hipMemsetAsync(h0hi, 0, (size_t)BATCH * HDIM * 2 * sizeof(u16), stream);  // h_0 = 0

  gather_xp<<<TSTEPS, 256, 0, stream>>>(inputs, perm, xp);
  build_X<<<(HDIM * HDIM) / 256, 256, 0, stream>>>(W_skew, X);

  // expm(A) = (T6(A/32))^(2^5), Horner -- fp32 gemm512 [proven numerics]
  axpyI<<<(HDIM * HDIM) / 256, 256, 0, stream>>>(P, X, 1.f / 6.f);
  float* a = P;
  float* b = Q;
  for (int k = 5; k >= 1; --k) {
    gemm512<<<dim3(8, 8), dim3(16, 16), 0, stream>>>(b, X, a, 1.f / (float)k, 1);
    float* tmp = a; a = b; b = tmp;
  }
  for (int i = 0; i < 5; ++i) {
    gemm512<<<dim3(8, 8), dim3(16, 16), 0, stream>>>(b, a, a, 1.f, 0);
    float* tmp = a; a = b; b = tmp;
  }
  // a == P (10 swaps -> back to P)

  rnn_main<<<NWG, 1024, 0, stream>>>(xp, a, W_in, b_mod, W_lin, b_lin, h0hi, h0lo,
                                     h1hi, h1lo, flags, out);
  (void)in_sizes; (void)n_in; (void)out_size; (void)ws_size;
}

// Round 16
// 2578.248 us; speedup vs baseline: 5.1816x; 3.1377x over previous
//
#include <hip/hip_runtime.h>

#define TSTEPS 784
#define BATCH  256
#define HDIM   512
#define NCLS   10
#define NGRP   16
#define WGPG   8

typedef __bf16 bf16x8 __attribute__((ext_vector_type(8)));
typedef float  f32x4  __attribute__((ext_vector_type(4)));
typedef unsigned uint4v __attribute__((ext_vector_type(4)));
typedef unsigned long long u64;
typedef unsigned short u16;

static __device__ __forceinline__ u16 f2bf(float f) {
  unsigned u = __builtin_bit_cast(unsigned, f);
  u += 0x7fffu + ((u >> 16) & 1u);
  return (u16)(u >> 16);
}
static __device__ __forceinline__ float bf2f(unsigned s) {
  unsigned u = s << 16;
  return __builtin_bit_cast(float, u);
}

// ---------------- xp[t][b] = inputs[b][perm[t]] ----------------
__global__ __launch_bounds__(256) void gather_xp(const float* __restrict__ in,
                                                 const int* __restrict__ perm,
                                                 float* __restrict__ xp) {
  int t = blockIdx.x;
  int b = threadIdx.x;
  int p = perm[t];
  p = (p < 0) ? 0 : (p >= TSTEPS ? TSTEPS - 1 : p);
  xp[t * BATCH + b] = in[b * TSTEPS + p];
}

// ---------------- X = (triu(W,1) - triu(W,1)^T) / 32 ----------------
__global__ __launch_bounds__(256) void build_X(const float* __restrict__ W,
                                               float* __restrict__ X) {
  int idx = blockIdx.x * 256 + threadIdx.x;
  int i = idx >> 9, j = idx & 511;
  float v = 0.f;
  if (j > i) v = W[i * HDIM + j];
  else if (i > j) v = -W[j * HDIM + i];
  X[idx] = v * 0.03125f;
}

// ---------------- P = coef*X + I ----------------
__global__ __launch_bounds__(256) void axpyI(float* __restrict__ P,
                                             const float* __restrict__ X, float coef) {
  int idx = blockIdx.x * 256 + threadIdx.x;
  int i = idx >> 9, j = idx & 511;
  P[idx] = coef * X[idx] + ((i == j) ? 1.f : 0.f);
}

// ---------------- C = alpha*A*B (+I), 512^3 fp32, BK=64 slabs ----------------
// Same 64x64 tile / 4x4-per-thread / k-ascending summation (bitwise-identical
// Borth to the R2-R15 chain); BK 16 -> 64 cuts barriers 64 -> 16 per gemm.
// As/Bs pad 69: staging write conflicts <= 2-way (free, m136); compute reads
// are broadcast (As) / contiguous (Bs).
__global__ __launch_bounds__(256) void gemm512(float* __restrict__ C,
                                               const float* __restrict__ A,
                                               const float* __restrict__ B,
                                               float alpha, int addI) {
  __shared__ float As[64][69];  // [kk][row] 17.6 KB
  __shared__ float Bs[64][69];  // [kk][col] 17.6 KB
  const int tx = threadIdx.x, ty = threadIdx.y;
  const int tid = ty * 16 + tx;
  const int ib = blockIdx.y, jb = blockIdx.x;
  const int ra = tid >> 2;              // 0..63: A row / B k-row staged by this thread
  const int ca = (tid & 3) << 4;        // 0,16,32,48: k/col offset
  float acc[4][4] = {};
  for (int kt = 0; kt < 8; ++kt) {
    f32x4 av[4], bv[4];
#pragma unroll
    for (int j4 = 0; j4 < 4; ++j4) {
      av[j4] = *(const f32x4*)(A + (ib * 64 + ra) * HDIM + kt * 64 + ca + (j4 << 2));
      bv[j4] = *(const f32x4*)(B + (kt * 64 + ra) * HDIM + jb * 64 + ca + (j4 << 2));
    }
    __syncthreads();  // previous slab's compute reads complete
#pragma unroll
    for (int j4 = 0; j4 < 4; ++j4) {
#pragma unroll
      for (int j = 0; j < 4; ++j) As[ca + (j4 << 2) + j][ra] = av[j4][j];  // transpose
      *(f32x4*)&Bs[ra][ca + (j4 << 2)] = bv[j4];
    }
    __syncthreads();
#pragma unroll
    for (int kk = 0; kk < 64; ++kk) {
      f32x4 a4 = *(const f32x4*)&As[kk][ty << 2];
      f32x4 b4 = *(const f32x4*)&Bs[kk][tx << 2];
#pragma unroll
      for (int u = 0; u < 4; ++u)
#pragma unroll
        for (int v = 0; v < 4; ++v) acc[u][v] = fmaf(a4[u], b4[v], acc[u][v]);
    }
  }
#pragma unroll
  for (int u = 0; u < 4; ++u)
#pragma unroll
    for (int v = 0; v < 4; ++v) {
      int r = ib * 64 + (ty << 2) + u, c = jb * 64 + (tx << 2) + v;
      float val = alpha * acc[u][v];
      if (addI && r == c) val += 1.f;
      C[r * HDIM + c] = val;
    }
}

// ---------------- persistent RNN scan [BYTE-EXACT R10: proven 2236 us] ----------------
// 128 WGs x 256 thr. gb = wg&15, cg = wg>>4. h in global as hi/lo u16 planes ->
// fragment ds_read_b128 yields bf16x8 directly. Flag barrier: 8 WGs/group.
// Swizzle: phys_dword = (row<<8) | (dcol ^ ((row&7)<<2)) on 256-dword rows.
__global__ __launch_bounds__(256, 1) void rnn_main(
    const float* __restrict__ xp, const float* __restrict__ Borth,
    const float* __restrict__ W_in, const float* __restrict__ b_mod,
    const float* __restrict__ W_lin, const float* __restrict__ b_lin,
    u16* __restrict__ h0hi, u16* __restrict__ h0lo, u16* __restrict__ h1hi,
    u16* __restrict__ h1lo, unsigned* __restrict__ flags, float* __restrict__ out) {
  __shared__ unsigned tileHi[4096], tileLo[4096];  // 16 KB + 16 KB

  const int wg = blockIdx.x;
  const int gb = wg & 15;
  const int cg = wg >> 4;
  const int tid = threadIdx.x;
  const int wave = tid >> 6;
  const int lane = tid & 63;
  const int quad = lane >> 4;
  const int l16 = lane & 15;
  const int colg = (cg << 6) + (wave << 4) + l16;

  // B fragments, AGPR-resident (round-hi split, proven numerics)
  bf16x8 Bfh[16], Bfl[16];
#pragma unroll
  for (int ki = 0; ki < 16; ++ki) {
#pragma unroll
    for (int j = 0; j < 8; ++j) {
      int k = (ki << 5) + (quad << 3) + j;
      float v = Borth[k * HDIM + colg];
      u16 hb = f2bf(v);
      u16 lb = f2bf(v - bf2f(hb));
      Bfh[ki][j] = __builtin_bit_cast(__bf16, hb);
      Bfl[ki][j] = __builtin_bit_cast(__bf16, lb);
    }
  }
  const float win = W_in[colg];
  const float bm = b_mod[colg];

  u16* const g0h = h0hi + (gb << 13);  // 8192 u16 per group-plane
  u16* const g0l = h0lo + (gb << 13);
  u16* const g1h = h1hi + (gb << 13);
  u16* const g1l = h1lo + (gb << 13);
  unsigned* const myflag = flags + ((gb << 3) + cg) * 32;
  unsigned* const gflags = flags + (gb << 3) * 32;
  const unsigned swz = (unsigned)((l16 & 7) << 2);

  for (int t = 0; t < TSTEPS; ++t) {
    const u64* __restrict__ cH = (const u64*)((t & 1) ? g1h : g0h);
    const u64* __restrict__ cL = (const u64*)((t & 1) ? g1l : g0l);
    u16* __restrict__ nH = (t & 1) ? g0h : g1h;
    u16* __restrict__ nL = (t & 1) ? g0l : g1l;

    // ---- cooperative stage: 2048 u64 per plane; 16 loads in flight ----
    u64 qh[8], ql[8];
#pragma unroll
    for (int i = 0; i < 8; ++i) {
      qh[i] = __hip_atomic_load(cH + tid + (i << 8), __ATOMIC_RELAXED,
                                __HIP_MEMORY_SCOPE_AGENT);
      ql[i] = __hip_atomic_load(cL + tid + (i << 8), __ATOMIC_RELAXED,
                                __HIP_MEMORY_SCOPE_AGENT);
    }
#pragma unroll
    for (int i = 0; i < 8; ++i) {
      int f = tid + (i << 8);        // u64 index in 2048-u64 plane
      int r = f >> 7;                // row 0..15
      unsigned du = (unsigned)(f & 127) << 1;  // dword col (even)
      unsigned phys = ((unsigned)r << 8) | (du ^ ((r & 7) << 2));
      *(u64*)(tileHi + phys) = qh[i];
      *(u64*)(tileLo + phys) = ql[i];
    }
    __syncthreads();

    // ---- fragment reads (swizzled, NO perms) + split-bf16 MFMA ----
    f32x4 a_hh = {0.f, 0.f, 0.f, 0.f};
    f32x4 a_lh = {0.f, 0.f, 0.f, 0.f};
    f32x4 a_hl = {0.f, 0.f, 0.f, 0.f};
#pragma unroll
    for (int ki = 0; ki < 16; ++ki) {
      unsigned dcol0 = (unsigned)((ki << 4) + (quad << 2));
      unsigned off = ((unsigned)l16 << 8) + (dcol0 ^ swz);
      bf16x8 ah = __builtin_bit_cast(bf16x8, *(const uint4v*)(tileHi + off));
      bf16x8 al = __builtin_bit_cast(bf16x8, *(const uint4v*)(tileLo + off));
      a_hh = __builtin_amdgcn_mfma_f32_16x16x32_bf16(ah, Bfh[ki], a_hh, 0, 0, 0);
      a_lh = __builtin_amdgcn_mfma_f32_16x16x32_bf16(al, Bfh[ki], a_lh, 0, 0, 0);
      a_hl = __builtin_amdgcn_mfma_f32_16x16x32_bf16(ah, Bfl[ki], a_hl, 0, 0, 0);
    }

    // C/D layout: row = quad*4 + r, col = l16  [R3-proven]
    const f32x4 xps = *(const f32x4*)(xp + t * BATCH + (gb << 4) + (quad << 2));
#pragma unroll
    for (int r = 0; r < 4; ++r) {
      float pre = a_hh[r] + a_lh[r] + a_hl[r] + xps[r] * win;
      float mm = fmaxf(fabsf(pre) + bm, 0.f);
      float hv = (pre > 0.f) ? mm : ((pre < 0.f) ? -mm : 0.f);
      int idx = (((quad << 2) + r) << 9) + colg;
      u16 hbv = f2bf(hv);
      u16 lbv = f2bf(hv - bf2f(hbv));
      __hip_atomic_store(nH + idx, hbv, __ATOMIC_RELAXED, __HIP_MEMORY_SCOPE_AGENT);
      __hip_atomic_store(nL + idx, lbv, __ATOMIC_RELAXED, __HIP_MEMORY_SCOPE_AGENT);
    }

    // ---- flag barrier (8 WGs per group) [R6-proven] ----
    asm volatile("s_waitcnt vmcnt(0)" ::: "memory");  // both planes at coherence point
    __syncthreads();
    if (tid == 0)
      __hip_atomic_store(myflag, (unsigned)(t + 1), __ATOMIC_RELAXED,
                         __HIP_MEMORY_SCOPE_AGENT);
    const unsigned target = (unsigned)(t + 1);
    int spin = 0;
    for (;;) {
      unsigned fl = __hip_atomic_load(gflags + (lane & 7) * 32, __ATOMIC_RELAXED,
                                      __HIP_MEMORY_SCOPE_AGENT);
      if (__ballot(fl >= target) == ~0ull) break;
      __builtin_amdgcn_s_sleep(1);
      if (++spin > (1 << 22)) break;  // anti-hang valve
    }
  }

  // ---- head: final h in buffer 0 (t=783 odd -> writes g0) ----
  if (cg == 0) {
    int row = tid >> 4;
    int cls = tid & 15;
    if (cls < NCLS) {
      const u16* hh = g0h + (row << 9);
      const u16* hl = g0l + (row << 9);
      float s = b_lin[cls];
      const float* wl = W_lin + cls * HDIM;
      for (int k = 0; k < HDIM; ++k) {
        unsigned hu = __hip_atomic_load(hh + k, __ATOMIC_RELAXED, __HIP_MEMORY_SCOPE_AGENT);
        unsigned lu = __hip_atomic_load(hl + k, __ATOMIC_RELAXED, __HIP_MEMORY_SCOPE_AGENT);
        s = fmaf(bf2f(hu) + bf2f(lu), wl[k], s);
      }
      out[((gb << 4) + row) * NCLS + cls] = s;
    }
  }
}

extern "C" void kernel_launch(void* const* d_in, const int* in_sizes, int n_in,
                              void* d_out, int out_size, void* d_ws, size_t ws_size,
                              hipStream_t stream) {
  const float* inputs = (const float*)d_in[0];  // 256x784
  const int* perm = (const int*)d_in[1];        // 784 (int64 -> int32 by harness)
  const float* W_skew = (const float*)d_in[2];  // 512x512
  const float* W_in = (const float*)d_in[3];    // 512
  const float* b_mod = (const float*)d_in[4];   // 512
  const float* W_lin = (const float*)d_in[5];   // 10x512
  const float* b_lin = (const float*)d_in[6];   // 10
  float* out = (float*)d_out;

  char* ws = (char*)d_ws;
  unsigned* flags = (unsigned*)ws;            // 32 KB
  u16* h0hi = (u16*)(ws + 32768);             // 4 planes x 256 KB = 1 MB
  u16* h0lo = h0hi + BATCH * HDIM;
  u16* h1hi = h0lo + BATCH * HDIM;
  u16* h1lo = h1hi + BATCH * HDIM;
  float* xp = (float*)(h1lo + BATCH * HDIM);  // 0.77 MB
  float* X = xp + TSTEPS * BATCH;             // 1 MB
  float* P = X + HDIM * HDIM;                 // 1 MB
  float* Q = P + HDIM * HDIM;                 // 1 MB  (total ~4.9 MB)

  hipMemsetAsync(flags, 0, 32768, stream);
  hipMemsetAsync(h0hi, 0, (size_t)BATCH * HDIM * 2 * sizeof(u16), stream);  // h0 hi+lo

  gather_xp<<<TSTEPS, 256, 0, stream>>>(inputs, perm, xp);
  build_X<<<(HDIM * HDIM) / 256, 256, 0, stream>>>(W_skew, X);

  // expm(A) = (T6(A/32))^(2^5), Horner -- fp32 gemm512 (BK=64), bitwise-identical
  // summation order to the proven chain
  axpyI<<<(HDIM * HDIM) / 256, 256, 0, stream>>>(P, X, 1.f / 6.f);
  float* a = P;
  float* b = Q;
  for (int k = 5; k >= 1; --k) {
    gemm512<<<dim3(8, 8), dim3(16, 16), 0, stream>>>(b, X, a, 1.f / (float)k, 1);
    float* tmp = a; a = b; b = tmp;
  }
  for (int i = 0; i < 5; ++i) {
    gemm512<<<dim3(8, 8), dim3(16, 16), 0, stream>>>(b, a, a, 1.f, 0);
    float* tmp = a; a = b; b = tmp;
  }
  // a == P (10 swaps -> back to P)

  rnn_main<<<NGRP * WGPG, 256, 0, stream>>>(xp, a, W_in, b_mod, W_lin, b_lin,
                                            h0hi, h0lo, h1hi, h1lo, flags, out);
  (void)in_sizes; (void)n_in; (void)out_size; (void)ws_size;
}